// Round 1
// baseline (905.420 us; speedup 1.0000x reference)
//
#include <hip/hip_runtime.h>

// Pipeline:
//   x[512,1,112,112] --conv1(3x3,1->8)+bias+relu+maxpool2--> h[512,8,56,56]   (ws)
//   h --conv2(3x3,8->16)+bias+relu+maxpool2--> f[512,16,28,28]                (ws)
//   f --2x2 patch-linear(64->4) -> pf[512,784] --fc1(784->64)+relu--> h1[512,64]
//     --fc2(64->10) --log_softmax--> out[512,10]
// All fp32.

// ---------------- Kernel A: conv1 + relu + maxpool2 ----------------
// One thread per pooled output element (b, c, py, px); 512*8*56*56 total.
__global__ __launch_bounds__(256) void k_conv1(const float* __restrict__ x,
                                               const float* __restrict__ w,
                                               const float* __restrict__ bias,
                                               float* __restrict__ out) {
  int idx = blockIdx.x * 256 + threadIdx.x;
  const int total = 512 * 8 * 56 * 56;
  if (idx >= total) return;
  int px = idx % 56;
  int t = idx / 56;
  int py = t % 56;
  t /= 56;
  int c = t & 7;
  int b = t >> 3;
  const float* xb = x + (long)b * 112 * 112;

  float wk[9];
#pragma unroll
  for (int k = 0; k < 9; ++k) wk[k] = w[c * 9 + k];

  // 4x4 input window covering the 2x2 conv taps under this pool cell
  float win[4][4];
  int iy0 = 2 * py - 1, ix0 = 2 * px - 1;
#pragma unroll
  for (int r = 0; r < 4; ++r) {
    int iy = iy0 + r;
    bool yok = (unsigned)iy < 112u;
#pragma unroll
    for (int q = 0; q < 4; ++q) {
      int ix = ix0 + q;
      win[r][q] = (yok && (unsigned)ix < 112u) ? xb[iy * 112 + ix] : 0.f;
    }
  }
  float m = -1e30f;
#pragma unroll
  for (int dy = 0; dy < 2; ++dy)
#pragma unroll
    for (int dx = 0; dx < 2; ++dx) {
      float s = 0.f;
#pragma unroll
      for (int ky = 0; ky < 3; ++ky)
#pragma unroll
        for (int kx = 0; kx < 3; ++kx) s += win[dy + ky][dx + kx] * wk[ky * 3 + kx];
      m = fmaxf(m, s);
    }
  // max(relu(v+b)) == relu(max(v)+b): bias uniform over the pool window
  out[idx] = fmaxf(m + bias[c], 0.f);
}

// ---------------- Kernel B: conv2 + relu + maxpool2 ----------------
// grid = (ceil(784/256), 512*16); thread per pooled output pixel of one (b,oc) plane.
__global__ __launch_bounds__(256) void k_conv2(const float* __restrict__ h,
                                               const float* __restrict__ w,
                                               const float* __restrict__ bias,
                                               float* __restrict__ out) {
  __shared__ float ws[16 * 8 * 9];  // 1152 floats
  for (int i = threadIdx.x; i < 1152; i += 256) ws[i] = w[i];
  __syncthreads();

  int pix = blockIdx.x * 256 + threadIdx.x;  // 0..783
  int oc = blockIdx.y & 15;
  int b = blockIdx.y >> 4;
  if (pix >= 784) return;
  int px = pix % 28, py = pix / 28;
  const float* hb = h + (long)b * 8 * 56 * 56;
  const float* wc = ws + oc * 72;

  float acc00 = 0.f, acc01 = 0.f, acc10 = 0.f, acc11 = 0.f;
  int iy0 = 2 * py - 1, ix0 = 2 * px - 1;
#pragma unroll
  for (int ic = 0; ic < 8; ++ic) {
    const float* hc = hb + ic * 56 * 56;
    float win[4][4];
#pragma unroll
    for (int r = 0; r < 4; ++r) {
      int iy = iy0 + r;
      bool yok = (unsigned)iy < 56u;
#pragma unroll
      for (int q = 0; q < 4; ++q) {
        int ix = ix0 + q;
        win[r][q] = (yok && (unsigned)ix < 56u) ? hc[iy * 56 + ix] : 0.f;
      }
    }
    const float* wic = wc + ic * 9;
    float w0 = wic[0], w1 = wic[1], w2 = wic[2], w3 = wic[3], w4 = wic[4],
          w5 = wic[5], w6 = wic[6], w7 = wic[7], w8 = wic[8];
    acc00 += win[0][0] * w0 + win[0][1] * w1 + win[0][2] * w2 +
             win[1][0] * w3 + win[1][1] * w4 + win[1][2] * w5 +
             win[2][0] * w6 + win[2][1] * w7 + win[2][2] * w8;
    acc01 += win[0][1] * w0 + win[0][2] * w1 + win[0][3] * w2 +
             win[1][1] * w3 + win[1][2] * w4 + win[1][3] * w5 +
             win[2][1] * w6 + win[2][2] * w7 + win[2][3] * w8;
    acc10 += win[1][0] * w0 + win[1][1] * w1 + win[1][2] * w2 +
             win[2][0] * w3 + win[2][1] * w4 + win[2][2] * w5 +
             win[3][0] * w6 + win[3][1] * w7 + win[3][2] * w8;
    acc11 += win[1][1] * w0 + win[1][2] * w1 + win[1][3] * w2 +
             win[2][1] * w3 + win[2][2] * w4 + win[2][3] * w5 +
             win[3][1] * w6 + win[3][2] * w7 + win[3][3] * w8;
  }
  float m = fmaxf(fmaxf(acc00, acc01), fmaxf(acc10, acc11));
  out[((long)b * 16 + oc) * 784 + pix] = fmaxf(m + bias[oc], 0.f);
}

// ---------------- Kernel C: patch-linear + fc1 + fc2 + log_softmax ----------------
// One block per batch element. f[b] (12544 floats = 50 KB) staged in LDS.
__global__ __launch_bounds__(256) void k_head(const float* __restrict__ f,
                                              const float* __restrict__ w_patch,
                                              const float* __restrict__ b_patch,
                                              const float* __restrict__ w_fc1,
                                              const float* __restrict__ b_fc1,
                                              const float* __restrict__ w_fc2,
                                              const float* __restrict__ b_fc2,
                                              float* __restrict__ out) {
  __shared__ float fs[12544];  // f[b] as [c][y][x]
  __shared__ float pfs[784];   // pf flattened: index = p*4 + o
  __shared__ float wps[256];   // w_patch [4][64]
  __shared__ float h1s[64];
  __shared__ float lg[10];
  int tid = threadIdx.x;
  int b = blockIdx.x;
  const float* fb = f + (long)b * 12544;
  for (int i = tid; i < 12544; i += 256) fs[i] = fb[i];
  if (tid < 256) {
    // w_patch is exactly 256 floats
    wps[tid] = w_patch[tid];
  }
  __syncthreads();

  // patch-linear: pf[p,o] = b_patch[o] + sum_{c,dy,dx} f[c,2ph+dy,2pw+dx]*wp[o, c*4+dy*2+dx]
  for (int t = tid; t < 784; t += 256) {
    int o = t & 3, p = t >> 2;
    int ph = p / 14, pw = p % 14;
    const float* wo = wps + o * 64;
    float s = b_patch[o];
#pragma unroll
    for (int c = 0; c < 16; ++c) {
      const float* fc = fs + c * 784 + (2 * ph) * 28 + 2 * pw;
      const float* wc = wo + c * 4;
      s += fc[0] * wc[0] + fc[1] * wc[1] + fc[28] * wc[2] + fc[29] * wc[3];
    }
    pfs[t] = s;
  }
  __syncthreads();

  // fc1: wave w computes j in [w*16, w*16+16); coalesced w_fc1 reads, 64-lane reduce
  int wave = tid >> 6, lane = tid & 63;
#pragma unroll 1
  for (int jj = 0; jj < 16; ++jj) {
    int j = wave * 16 + jj;
    const float* wj = w_fc1 + j * 784;
    float part = 0.f;
    for (int i = lane; i < 784; i += 64) part += pfs[i] * wj[i];
#pragma unroll
    for (int off = 32; off > 0; off >>= 1) part += __shfl_down(part, off, 64);
    if (lane == 0) h1s[j] = fmaxf(part + b_fc1[j], 0.f);
  }
  __syncthreads();

  // fc2
  if (tid < 10) {
    float s = b_fc2[tid];
    const float* wo = w_fc2 + tid * 64;
#pragma unroll
    for (int j = 0; j < 64; ++j) s += h1s[j] * wo[j];
    lg[tid] = s;
  }
  __syncthreads();

  // log_softmax over 10 logits
  if (tid == 0) {
    float mx = lg[0];
    for (int o = 1; o < 10; ++o) mx = fmaxf(mx, lg[o]);
    float se = 0.f;
    for (int o = 0; o < 10; ++o) se += expf(lg[o] - mx);
    float lse = mx + logf(se);
    for (int o = 0; o < 10; ++o) out[b * 10 + o] = lg[o] - lse;
  }
}

extern "C" void kernel_launch(void* const* d_in, const int* in_sizes, int n_in,
                              void* d_out, int out_size, void* d_ws, size_t ws_size,
                              hipStream_t stream) {
  const float* x = (const float*)d_in[0];
  const float* w1 = (const float*)d_in[1];
  const float* b1 = (const float*)d_in[2];
  const float* w2 = (const float*)d_in[3];
  const float* b2 = (const float*)d_in[4];
  const float* wp = (const float*)d_in[5];
  const float* bp = (const float*)d_in[6];
  const float* wf1 = (const float*)d_in[7];
  const float* bf1 = (const float*)d_in[8];
  const float* wf2 = (const float*)d_in[9];
  const float* bf2 = (const float*)d_in[10];

  float* h = (float*)d_ws;            // 512*8*56*56  = 12,845,056 floats (51.4 MB)
  float* f = h + 12845056;            // 512*16*28*28 =  6,422,528 floats (25.7 MB)

  {
    const int total = 512 * 8 * 56 * 56;
    k_conv1<<<dim3((total + 255) / 256), 256, 0, stream>>>(x, w1, b1, h);
  }
  k_conv2<<<dim3(4, 512 * 16), 256, 0, stream>>>(h, w2, b2, f);
  k_head<<<dim3(512), 256, 0, stream>>>(f, wp, bp, wf1, bf1, wf2, bf2,
                                        (float*)d_out);
}

// Round 3
// 230.243 us; speedup vs baseline: 3.9325x; 3.9325x over previous
//
#include <hip/hip_runtime.h>

// Pipeline:
//   x[512,1,112,112] --conv1(3x3,1->8)+bias+relu+maxpool2--> h[512,8,56,56]   (ws)
//   h --conv2(3x3,8->16)+bias+relu+maxpool2--> f[512,16,28,28]                (ws)
//   f --2x2 patch-linear(64->4) -> pf[512,784] --fc1(784->64)+relu--> h1[512,64]
//     --fc2(64->10) --log_softmax--> out[512,10]
// All fp32.

// ---------------- Kernel A: conv1 + relu + maxpool2, all 8 oc per thread ----
// One thread per pooled pixel (b, py, px); computes all 8 output channels.
// 512*56*56 = 1,605,632 threads = 6272 blocks.
__global__ __launch_bounds__(256) void k_conv1(const float* __restrict__ x,
                                               const float* __restrict__ w,
                                               const float* __restrict__ bias,
                                               float* __restrict__ out) {
  __shared__ __align__(16) float ws[8 * 12];  // [c][12], 9 taps + pad
  if (threadIdx.x < 96) {
    int c = threadIdx.x / 12, k = threadIdx.x % 12;
    ws[threadIdx.x] = (k < 9) ? w[c * 9 + k] : 0.f;
  }
  __syncthreads();

  int idx = blockIdx.x * 256 + threadIdx.x;  // = b*3136 + pix
  int pix = idx % 3136;
  int b = idx / 3136;
  int px = pix % 56, py = pix / 56;
  const float* xb = x + (long)b * 12544;  // x batch stride: 112*112

  // 4x4 input window covering the 2x2 conv taps under this pool cell
  float win[4][4];
  int iy0 = 2 * py - 1, ix0 = 2 * px - 1;
#pragma unroll
  for (int r = 0; r < 4; ++r) {
    int iy = iy0 + r;
    bool yok = (unsigned)iy < 112u;
#pragma unroll
    for (int q = 0; q < 4; ++q) {
      int ix = ix0 + q;
      win[r][q] = (yok && (unsigned)ix < 112u) ? xb[iy * 112 + ix] : 0.f;
    }
  }

#pragma unroll
  for (int c = 0; c < 8; ++c) {
    const float4* wq = (const float4*)(ws + c * 12);
    float4 q0 = wq[0], q1 = wq[1], q2 = wq[2];
    float w0 = q0.x, w1 = q0.y, w2 = q0.z, w3 = q0.w, w4 = q1.x, w5 = q1.y,
          w6 = q1.z, w7 = q1.w, w8 = q2.x;
    float s00 = win[0][0] * w0 + win[0][1] * w1 + win[0][2] * w2 +
                win[1][0] * w3 + win[1][1] * w4 + win[1][2] * w5 +
                win[2][0] * w6 + win[2][1] * w7 + win[2][2] * w8;
    float s01 = win[0][1] * w0 + win[0][2] * w1 + win[0][3] * w2 +
                win[1][1] * w3 + win[1][2] * w4 + win[1][3] * w5 +
                win[2][1] * w6 + win[2][2] * w7 + win[2][3] * w8;
    float s10 = win[1][0] * w0 + win[1][1] * w1 + win[1][2] * w2 +
                win[2][0] * w3 + win[2][1] * w4 + win[2][2] * w5 +
                win[3][0] * w6 + win[3][1] * w7 + win[3][2] * w8;
    float s11 = win[1][1] * w0 + win[1][2] * w1 + win[1][3] * w2 +
                win[2][1] * w3 + win[2][2] * w4 + win[2][3] * w5 +
                win[3][1] * w6 + win[3][2] * w7 + win[3][3] * w8;
    float m = fmaxf(fmaxf(s00, s01), fmaxf(s10, s11));
    // max(relu(v+b)) == relu(max(v)+b)
    out[((long)b * 8 + c) * 3136 + pix] = fmaxf(m + bias[c], 0.f);
  }
}

// ---------------- Kernel B: conv2 + relu + maxpool2, all 16 oc per thread ---
// One thread per pooled pixel (b, py, px); computes all 16 output channels.
// 512*784 = 401,408 threads = 1568 blocks. 64 fp32 accumulators per thread.
__global__ __launch_bounds__(256) void k_conv2(const float* __restrict__ h,
                                               const float* __restrict__ w,
                                               const float* __restrict__ bias,
                                               float* __restrict__ out) {
  __shared__ __align__(16) float ws[8 * 16 * 12];  // [ic][oc][12]: 9 taps + pad
  for (int t = threadIdx.x; t < 1536; t += 256) {
    int k = t % 12;
    int rest = t / 12;
    int oc = rest % 16, ic = rest / 16;
    ws[t] = (k < 9) ? w[(oc * 8 + ic) * 9 + k] : 0.f;
  }
  __syncthreads();

  int idx = blockIdx.x * 256 + threadIdx.x;  // = b*784 + pix
  int pix = idx % 784;
  int b = idx / 784;
  int px = pix % 28, py = pix / 28;
  const float* hb = h + (long)b * 25088;  // h batch stride: 8*56*56 = 25088 (R1 bug: was 6272)

  float a00[16], a01[16], a10[16], a11[16];
#pragma unroll
  for (int oc = 0; oc < 16; ++oc) a00[oc] = a01[oc] = a10[oc] = a11[oc] = 0.f;

  int iy0 = 2 * py - 1, ix0 = 2 * px - 1;
#pragma unroll 1
  for (int ic = 0; ic < 8; ++ic) {
    const float* hc = hb + ic * 3136;
    float win[4][4];
#pragma unroll
    for (int r = 0; r < 4; ++r) {
      int iy = iy0 + r;
      bool yok = (unsigned)iy < 56u;
#pragma unroll
      for (int q = 0; q < 4; ++q) {
        int ix = ix0 + q;
        win[r][q] = (yok && (unsigned)ix < 56u) ? hc[iy * 56 + ix] : 0.f;
      }
    }
    const float* wbase = ws + ic * 192;  // 16*12 per ic
#pragma unroll
    for (int oc = 0; oc < 16; ++oc) {
      const float4* wq = (const float4*)(wbase + oc * 12);
      float4 q0 = wq[0], q1 = wq[1], q2 = wq[2];
      float w0 = q0.x, w1 = q0.y, w2 = q0.z, w3 = q0.w, w4 = q1.x, w5 = q1.y,
            w6 = q1.z, w7 = q1.w, w8 = q2.x;
      a00[oc] += win[0][0] * w0 + win[0][1] * w1 + win[0][2] * w2 +
                 win[1][0] * w3 + win[1][1] * w4 + win[1][2] * w5 +
                 win[2][0] * w6 + win[2][1] * w7 + win[2][2] * w8;
      a01[oc] += win[0][1] * w0 + win[0][2] * w1 + win[0][3] * w2 +
                 win[1][1] * w3 + win[1][2] * w4 + win[1][3] * w5 +
                 win[2][1] * w6 + win[2][2] * w7 + win[2][3] * w8;
      a10[oc] += win[1][0] * w0 + win[1][1] * w1 + win[1][2] * w2 +
                 win[2][0] * w3 + win[2][1] * w4 + win[2][2] * w5 +
                 win[3][0] * w6 + win[3][1] * w7 + win[3][2] * w8;
      a11[oc] += win[1][1] * w0 + win[1][2] * w1 + win[1][3] * w2 +
                 win[2][1] * w3 + win[2][2] * w4 + win[2][3] * w5 +
                 win[3][1] * w6 + win[3][2] * w7 + win[3][3] * w8;
    }
  }

#pragma unroll
  for (int oc = 0; oc < 16; ++oc) {
    float m = fmaxf(fmaxf(a00[oc], a01[oc]), fmaxf(a10[oc], a11[oc]));
    out[((long)b * 16 + oc) * 784 + pix] = fmaxf(m + bias[oc], 0.f);
  }
}

// ---------------- Kernel C: patch-linear + fc1 + fc2 + log_softmax ----------
// One block per batch element. f[b] (12544 floats = 50 KB) staged in LDS.
__global__ __launch_bounds__(256) void k_head(const float* __restrict__ f,
                                              const float* __restrict__ w_patch,
                                              const float* __restrict__ b_patch,
                                              const float* __restrict__ w_fc1,
                                              const float* __restrict__ b_fc1,
                                              const float* __restrict__ w_fc2,
                                              const float* __restrict__ b_fc2,
                                              float* __restrict__ out) {
  __shared__ __align__(16) float fs[12544];  // f[b] as [c][y][x]
  __shared__ float pfs[784];                 // pf flattened: index = p*4 + o
  __shared__ float wps[256];                 // w_patch [4][64]
  __shared__ float h1s[64];
  __shared__ float lg[10];
  int tid = threadIdx.x;
  int b = blockIdx.x;
  const float4* fb4 = (const float4*)(f + (long)b * 12544);
  float4* fs4 = (float4*)fs;
  for (int i = tid; i < 3136; i += 256) fs4[i] = fb4[i];
  wps[tid] = w_patch[tid];  // exactly 256 floats
  __syncthreads();

  // patch-linear: pf[p,o] = b_patch[o] + sum_{c,dy,dx} f[c,2ph+dy,2pw+dx]*wp[o,c*4+dy*2+dx]
  for (int t = tid; t < 784; t += 256) {
    int o = t & 3, p = t >> 2;
    int ph = p / 14, pw = p % 14;
    const float* wo = wps + o * 64;
    float s = b_patch[o];
#pragma unroll
    for (int c = 0; c < 16; ++c) {
      const float* fc = fs + c * 784 + (2 * ph) * 28 + 2 * pw;
      const float* wc = wo + c * 4;
      s += fc[0] * wc[0] + fc[1] * wc[1] + fc[28] * wc[2] + fc[29] * wc[3];
    }
    pfs[t] = s;
  }
  __syncthreads();

  // fc1: wave w computes j in [w*16, w*16+16); coalesced w_fc1 reads, 64-lane reduce
  int wave = tid >> 6, lane = tid & 63;
#pragma unroll 1
  for (int jj = 0; jj < 16; ++jj) {
    int j = wave * 16 + jj;
    const float* wj = w_fc1 + j * 784;
    float part = 0.f;
    for (int i = lane; i < 784; i += 64) part += pfs[i] * wj[i];
#pragma unroll
    for (int off = 32; off > 0; off >>= 1) part += __shfl_down(part, off, 64);
    if (lane == 0) h1s[j] = fmaxf(part + b_fc1[j], 0.f);
  }
  __syncthreads();

  // fc2
  if (tid < 10) {
    float s = b_fc2[tid];
    const float* wo = w_fc2 + tid * 64;
#pragma unroll
    for (int j = 0; j < 64; ++j) s += h1s[j] * wo[j];
    lg[tid] = s;
  }
  __syncthreads();

  // log_softmax over 10 logits
  if (tid == 0) {
    float mx = lg[0];
    for (int o = 1; o < 10; ++o) mx = fmaxf(mx, lg[o]);
    float se = 0.f;
    for (int o = 0; o < 10; ++o) se += expf(lg[o] - mx);
    float lse = mx + logf(se);
    for (int o = 0; o < 10; ++o) out[b * 10 + o] = lg[o] - lse;
  }
}

extern "C" void kernel_launch(void* const* d_in, const int* in_sizes, int n_in,
                              void* d_out, int out_size, void* d_ws, size_t ws_size,
                              hipStream_t stream) {
  const float* x = (const float*)d_in[0];
  const float* w1 = (const float*)d_in[1];
  const float* b1 = (const float*)d_in[2];
  const float* w2 = (const float*)d_in[3];
  const float* b2 = (const float*)d_in[4];
  const float* wp = (const float*)d_in[5];
  const float* bp = (const float*)d_in[6];
  const float* wf1 = (const float*)d_in[7];
  const float* bf1 = (const float*)d_in[8];
  const float* wf2 = (const float*)d_in[9];
  const float* bf2 = (const float*)d_in[10];

  float* h = (float*)d_ws;            // 512*8*56*56  = 12,845,056 floats (51.4 MB)
  float* f = h + 12845056;            // 512*16*28*28 =  6,422,528 floats (25.7 MB)

  k_conv1<<<dim3(6272), 256, 0, stream>>>(x, w1, b1, h);
  k_conv2<<<dim3(1568), 256, 0, stream>>>(h, w2, b2, f);
  k_head<<<dim3(512), 256, 0, stream>>>(f, wp, bp, wf1, bf1, wf2, bf2,
                                        (float*)d_out);
}

// Round 4
// 209.502 us; speedup vs baseline: 4.3218x; 1.0990x over previous
//
#include <hip/hip_runtime.h>

// Pipeline:
//   x[512,1,112,112] --conv1(3x3,1->8)+bias+relu+maxpool2--> h[512,8,56,56]   (ws)
//   h --conv2(3x3,8->16)+bias+relu+maxpool2--> f[512,16,28,28]                (ws)
//   f --2x2 patch-linear(64->4) -> pf[512,784]                                (ws, reuses h)
//   pf --fc1(784->64)+relu--> fc2(64->10) --log_softmax--> out[512,10]
// All fp32.

// ---------------- Kernel A: conv1 + relu + maxpool2 -------------------------
// One thread per HORIZONTAL PAIR of pooled pixels (b, py, 2*pxp..2*pxp+1),
// all 8 output channels. 512*56*28 = 802,816 threads = 3136 blocks.
// Weights (72 floats) are read with wave-uniform indices -> scalar K$ loads.
__global__ __launch_bounds__(256) void k_conv1(const float* __restrict__ x,
                                               const float* __restrict__ w,
                                               const float* __restrict__ bias,
                                               float* __restrict__ out) {
  int idx = blockIdx.x * 256 + threadIdx.x;  // = b*1568 + pp
  int pp = idx % 1568;
  int b = idx / 1568;
  int pxp = pp % 28, py = pp / 28;  // pooled px = 2*pxp, 2*pxp+1
  const float* xb = x + (long)b * 12544;  // x batch stride 112*112

  // 4x6 input window covering both pooled pixels' conv taps
  float win[4][6];
  int iy0 = 2 * py - 1, ix0 = 4 * pxp - 1;
#pragma unroll
  for (int r = 0; r < 4; ++r) {
    int iy = iy0 + r;
    bool yok = (unsigned)iy < 112u;
#pragma unroll
    for (int q = 0; q < 6; ++q) {
      int ix = ix0 + q;
      win[r][q] = (yok && (unsigned)ix < 112u) ? xb[iy * 112 + ix] : 0.f;
    }
  }

#pragma unroll
  for (int c = 0; c < 8; ++c) {
    float w0 = w[c * 9 + 0], w1 = w[c * 9 + 1], w2 = w[c * 9 + 2],
          w3 = w[c * 9 + 3], w4 = w[c * 9 + 4], w5 = w[c * 9 + 5],
          w6 = w[c * 9 + 6], w7 = w[c * 9 + 7], w8 = w[c * 9 + 8];
    float m0, m1;
    {  // pixel 0: window cols 0..3
      float s00 = win[0][0]*w0 + win[0][1]*w1 + win[0][2]*w2 +
                  win[1][0]*w3 + win[1][1]*w4 + win[1][2]*w5 +
                  win[2][0]*w6 + win[2][1]*w7 + win[2][2]*w8;
      float s01 = win[0][1]*w0 + win[0][2]*w1 + win[0][3]*w2 +
                  win[1][1]*w3 + win[1][2]*w4 + win[1][3]*w5 +
                  win[2][1]*w6 + win[2][2]*w7 + win[2][3]*w8;
      float s10 = win[1][0]*w0 + win[1][1]*w1 + win[1][2]*w2 +
                  win[2][0]*w3 + win[2][1]*w4 + win[2][2]*w5 +
                  win[3][0]*w6 + win[3][1]*w7 + win[3][2]*w8;
      float s11 = win[1][1]*w0 + win[1][2]*w1 + win[1][3]*w2 +
                  win[2][1]*w3 + win[2][2]*w4 + win[2][3]*w5 +
                  win[3][1]*w6 + win[3][2]*w7 + win[3][3]*w8;
      m0 = fmaxf(fmaxf(s00, s01), fmaxf(s10, s11));
    }
    {  // pixel 1: window cols 2..5
      float s00 = win[0][2]*w0 + win[0][3]*w1 + win[0][4]*w2 +
                  win[1][2]*w3 + win[1][3]*w4 + win[1][4]*w5 +
                  win[2][2]*w6 + win[2][3]*w7 + win[2][4]*w8;
      float s01 = win[0][3]*w0 + win[0][4]*w1 + win[0][5]*w2 +
                  win[1][3]*w3 + win[1][4]*w4 + win[1][5]*w5 +
                  win[2][3]*w6 + win[2][4]*w7 + win[2][5]*w8;
      float s10 = win[1][2]*w0 + win[1][3]*w1 + win[1][4]*w2 +
                  win[2][2]*w3 + win[2][3]*w4 + win[2][4]*w5 +
                  win[3][2]*w6 + win[3][3]*w7 + win[3][4]*w8;
      float s11 = win[1][3]*w0 + win[1][4]*w1 + win[1][5]*w2 +
                  win[2][3]*w3 + win[2][4]*w4 + win[2][5]*w5 +
                  win[3][3]*w6 + win[3][4]*w7 + win[3][5]*w8;
      m1 = fmaxf(fmaxf(s00, s01), fmaxf(s10, s11));
    }
    float bc = bias[c];
    float2 st = make_float2(fmaxf(m0 + bc, 0.f), fmaxf(m1 + bc, 0.f));
    *(float2*)&out[((long)b * 8 + c) * 3136 + py * 56 + 2 * pxp] = st;
  }
}

// ---------------- Kernel B: conv2 + relu + maxpool2 -------------------------
// One thread per pooled pixel (b, py, px); 16 oc in two halves of 8 (keeps
// accumulators at 32 VGPRs). Weights read with wave-uniform indices -> scalar
// loads, no LDS. 512*784 = 401,408 threads = 1568 blocks.
__global__ __launch_bounds__(256) void k_conv2(const float* __restrict__ h,
                                               const float* __restrict__ w,
                                               const float* __restrict__ bias,
                                               float* __restrict__ out) {
  int idx = blockIdx.x * 256 + threadIdx.x;  // = b*784 + pix
  int pix = idx % 784;
  int b = idx / 784;
  int px = pix % 28, py = pix / 28;
  const float* hb = h + (long)b * 25088;  // h batch stride: 8*56*56
  int iy0 = 2 * py - 1, ix0 = 2 * px - 1;

#pragma unroll 1
  for (int half = 0; half < 2; ++half) {
    float a00[8], a01[8], a10[8], a11[8];
#pragma unroll
    for (int o = 0; o < 8; ++o) a00[o] = a01[o] = a10[o] = a11[o] = 0.f;

#pragma unroll 1
    for (int ic = 0; ic < 8; ++ic) {
      const float* hc = hb + ic * 3136;
      float win[4][4];
#pragma unroll
      for (int r = 0; r < 4; ++r) {
        int iy = iy0 + r;
        bool yok = (unsigned)iy < 56u;
#pragma unroll
        for (int q = 0; q < 4; ++q) {
          int ix = ix0 + q;
          win[r][q] = (yok && (unsigned)ix < 56u) ? hc[iy * 56 + ix] : 0.f;
        }
      }
#pragma unroll
      for (int o = 0; o < 8; ++o) {
        const float* wp_ = w + (((half * 8 + o) * 8 + ic) * 9);  // uniform addr
        float w0 = wp_[0], w1 = wp_[1], w2 = wp_[2], w3 = wp_[3], w4 = wp_[4],
              w5 = wp_[5], w6 = wp_[6], w7 = wp_[7], w8 = wp_[8];
        a00[o] += win[0][0]*w0 + win[0][1]*w1 + win[0][2]*w2 +
                  win[1][0]*w3 + win[1][1]*w4 + win[1][2]*w5 +
                  win[2][0]*w6 + win[2][1]*w7 + win[2][2]*w8;
        a01[o] += win[0][1]*w0 + win[0][2]*w1 + win[0][3]*w2 +
                  win[1][1]*w3 + win[1][2]*w4 + win[1][3]*w5 +
                  win[2][1]*w6 + win[2][2]*w7 + win[2][3]*w8;
        a10[o] += win[1][0]*w0 + win[1][1]*w1 + win[1][2]*w2 +
                  win[2][0]*w3 + win[2][1]*w4 + win[2][2]*w5 +
                  win[3][0]*w6 + win[3][1]*w7 + win[3][2]*w8;
        a11[o] += win[1][1]*w0 + win[1][2]*w1 + win[1][3]*w2 +
                  win[2][1]*w3 + win[2][2]*w4 + win[2][3]*w5 +
                  win[3][1]*w6 + win[3][2]*w7 + win[3][3]*w8;
      }
    }
#pragma unroll
    for (int o = 0; o < 8; ++o) {
      float m = fmaxf(fmaxf(a00[o], a01[o]), fmaxf(a10[o], a11[o]));
      int oc = half * 8 + o;
      out[((long)b * 16 + oc) * 784 + pix] = fmaxf(m + bias[oc], 0.f);
    }
  }
}

// ---------------- Kernel C1: patch-linear ----------------------------------
// Thread per (b, p, o): lane holds w_patch row o (64 VGPRs), reads 64 f values
// (shared by the 4 lanes of its p), writes pf[b][p*4+o]. 1568 blocks.
__global__ __launch_bounds__(256) void k_patch(const float* __restrict__ f,
                                               const float* __restrict__ w_patch,
                                               const float* __restrict__ b_patch,
                                               float* __restrict__ pf) {
  int idx = blockIdx.x * 256 + threadIdx.x;  // = (b*196 + p)*4 + o
  int o = idx & 3;
  int t = idx >> 2;
  int p = t % 196;
  int b = t / 196;
  int ph = p / 14, pw = p % 14;

  const float4* wo4 = (const float4*)(w_patch + o * 64);
  const float* fb = f + (long)b * 12544 + ph * 56 + pw * 2;  // [c][2ph][2pw]

  float s = b_patch[o];
#pragma unroll
  for (int c = 0; c < 16; ++c) {
    const float* fc = fb + c * 784;
    float4 wc = wo4[c];  // wp[o][c*4 + (dy*2+dx)]
    float2 r0 = *(const float2*)(fc);       // f[c][2ph][2pw..2pw+1]
    float2 r1 = *(const float2*)(fc + 28);  // f[c][2ph+1][2pw..2pw+1]
    s += r0.x * wc.x + r0.y * wc.y + r1.x * wc.z + r1.y * wc.w;
  }
  pf[idx] = s;
}

// ---------------- Kernel C2: fc1 + fc2 + log_softmax ------------------------
// One block per batch element, 256 threads. fc1: thread (j=tid/4, q=tid&3)
// reduces a 196-element quarter with float4, then width-4 shuffle combine.
__global__ __launch_bounds__(256) void k_fc(const float* __restrict__ pf,
                                            const float* __restrict__ w_fc1,
                                            const float* __restrict__ b_fc1,
                                            const float* __restrict__ w_fc2,
                                            const float* __restrict__ b_fc2,
                                            float* __restrict__ out) {
  __shared__ __align__(16) float pfs[784];
  __shared__ float h1s[64];
  __shared__ float lg[10];
  int tid = threadIdx.x;
  int b = blockIdx.x;

  if (tid < 196) ((float4*)pfs)[tid] = ((const float4*)(pf + (long)b * 784))[tid];
  __syncthreads();

  int j = tid >> 2, q = tid & 3;
  const float4* wj4 = (const float4*)(w_fc1 + j * 784 + q * 196);
  const float4* ps4 = (const float4*)(pfs + q * 196);
  float s = 0.f;
#pragma unroll 7
  for (int k = 0; k < 49; ++k) {
    float4 wv = wj4[k];
    float4 pv = ps4[k];
    s += wv.x * pv.x + wv.y * pv.y + wv.z * pv.z + wv.w * pv.w;
  }
  s += __shfl_down(s, 2, 4);
  s += __shfl_down(s, 1, 4);
  if (q == 0) h1s[j] = fmaxf(s + b_fc1[j], 0.f);
  __syncthreads();

  if (tid < 10) {
    float s2 = b_fc2[tid];
    const float* wo = w_fc2 + tid * 64;
#pragma unroll
    for (int k = 0; k < 64; ++k) s2 += h1s[k] * wo[k];
    lg[tid] = s2;
  }
  __syncthreads();

  if (tid == 0) {
    float mx = lg[0];
    for (int o = 1; o < 10; ++o) mx = fmaxf(mx, lg[o]);
    float se = 0.f;
    for (int o = 0; o < 10; ++o) se += expf(lg[o] - mx);
    float lse = mx + logf(se);
    for (int o = 0; o < 10; ++o) out[b * 10 + o] = lg[o] - lse;
  }
}

extern "C" void kernel_launch(void* const* d_in, const int* in_sizes, int n_in,
                              void* d_out, int out_size, void* d_ws, size_t ws_size,
                              hipStream_t stream) {
  const float* x = (const float*)d_in[0];
  const float* w1 = (const float*)d_in[1];
  const float* b1 = (const float*)d_in[2];
  const float* w2 = (const float*)d_in[3];
  const float* b2 = (const float*)d_in[4];
  const float* wp = (const float*)d_in[5];
  const float* bp = (const float*)d_in[6];
  const float* wf1 = (const float*)d_in[7];
  const float* bf1 = (const float*)d_in[8];
  const float* wf2 = (const float*)d_in[9];
  const float* bf2 = (const float*)d_in[10];

  float* h = (float*)d_ws;            // 512*8*56*56  = 12,845,056 floats (51.4 MB)
  float* f = h + 12845056;            // 512*16*28*28 =  6,422,528 floats (25.7 MB)
  float* pf = h;                      // h is dead after k_conv2; reuse for pf[512,784]

  k_conv1<<<dim3(3136), 256, 0, stream>>>(x, w1, b1, h);
  k_conv2<<<dim3(1568), 256, 0, stream>>>(h, w2, b2, f);
  k_patch<<<dim3(1568), 256, 0, stream>>>(f, wp, bp, pf);
  k_fc<<<dim3(512), 256, 0, stream>>>(pf, wf1, bf1, wf2, bf2, (float*)d_out);
}

// Round 5
// 172.999 us; speedup vs baseline: 5.2337x; 1.2110x over previous
//
#include <hip/hip_runtime.h>

// Fully fused pipeline (h and f never touch HBM):
//   k_fused: per (b, s half): conv1+relu+pool -> LDS h-tile -> conv2+relu+pool
//            -> 2x2 patch-linear -> pf[512,784]  (ws)
//   k_fc:    pf --fc1(784->64)+relu--> fc2(64->10) --log_softmax--> out[512,10]
// All fp32.

#define HS_STRIDE 59  // 58 used cols (56 + 2 halo) + 1 pad

// 9-tap conv dot at window offset (J,K)
#define C9(J, K)                                                        \
  (win[J][K] * w0_ + win[J][K + 1] * w1_ + win[J][K + 2] * w2_ +        \
   win[J + 1][K] * w3_ + win[J + 1][K + 1] * w4_ + win[J + 1][K + 2] * w5_ + \
   win[J + 2][K] * w6_ + win[J + 2][K + 1] * w7_ + win[J + 2][K + 2] * w8_)

__global__ __launch_bounds__(256) void k_fused(
    const float* __restrict__ x, const float* __restrict__ w1,
    const float* __restrict__ b1, const float* __restrict__ w2,
    const float* __restrict__ b2, const float* __restrict__ wp,
    const float* __restrict__ bp, float* __restrict__ pf) {
  // h tile: [ic=8][rows r=0..29][cols 0..57], col 0/57 and invalid rows = zero halo.
  // tile row r <-> global h row gr = 28*s - 1 + r.
  __shared__ float hs[8 * 30 * HS_STRIDE];  // 14160 floats = 56.6 KB
  __shared__ float pfh[98 * 8];             // [p_local][half][4] patch partials
  const int tid = threadIdx.x;
  const int b = blockIdx.x >> 1;
  const int s = blockIdx.x & 1;

  for (int i = tid; i < 8 * 30 * HS_STRIDE; i += 256) hs[i] = 0.f;
  __syncthreads();

  // ---- Phase 1: conv1(1->8)+bias+relu+maxpool2 into LDS tile ----
  // tasks: 30 tile rows x 56 cols; each computes all 8 channels.
  const float* xb = x + (long)b * 12544;  // x[b], 112x112
  for (int task = tid; task < 1680; task += 256) {
    int r = task / 56, hc = task % 56;
    int gr = 28 * s - 1 + r;             // global pooled-h row
    if ((unsigned)gr >= 56u) continue;   // halo row stays zero
    float win[4][4];
    int iy0 = 2 * gr - 1, ix0 = 2 * hc - 1;
#pragma unroll
    for (int rr = 0; rr < 4; ++rr) {
      int iy = iy0 + rr;
      bool yok = (unsigned)iy < 112u;
#pragma unroll
      for (int q = 0; q < 4; ++q) {
        int ix = ix0 + q;
        win[rr][q] = (yok && (unsigned)ix < 112u) ? xb[iy * 112 + ix] : 0.f;
      }
    }
#pragma unroll
    for (int c = 0; c < 8; ++c) {
      float w0_ = w1[c * 9 + 0], w1_ = w1[c * 9 + 1], w2_ = w1[c * 9 + 2],
            w3_ = w1[c * 9 + 3], w4_ = w1[c * 9 + 4], w5_ = w1[c * 9 + 5],
            w6_ = w1[c * 9 + 6], w7_ = w1[c * 9 + 7], w8_ = w1[c * 9 + 8];
      float s00 = C9(0, 0), s01 = C9(0, 1), s10 = C9(1, 0), s11 = C9(1, 1);
      float m = fmaxf(fmaxf(s00, s01), fmaxf(s10, s11));
      // max(relu(v+b)) == relu(max(v)+b)
      hs[(c * 30 + r) * HS_STRIDE + 1 + hc] = fmaxf(m + b1[c], 0.f);
    }
  }
  __syncthreads();

  // ---- Phase 2: conv2(8->16)+bias+relu+maxpool2 + patch-linear partials ----
  // thread (p_local, half): patch p covers f pixels (2ph+half, 2pw..2pw+1).
  // Computes that horizontal f-pixel pair for all 16 oc (two halves of 8),
  // then its dy=half contribution to pf[p][0..3].
  if (tid < 196) {
    int half = tid / 98;            // patch-row offset dy
    int p_l = tid - half * 98;      // 0..97
    int ph_l = p_l / 14, pw = p_l - ph_l * 14;
    int r0 = 4 * ph_l + 2 * half;   // tile row of window top
    int c0 = 4 * pw;                // tile col of window left
    float partial[4] = {0.f, 0.f, 0.f, 0.f};
#pragma unroll 1
    for (int oh = 0; oh < 2; ++oh) {
      float a[8][8];  // [o][pos]; pos 0-3 = pixel0 (00,01,10,11), 4-7 = pixel1
#pragma unroll
      for (int o = 0; o < 8; ++o)
#pragma unroll
        for (int q = 0; q < 8; ++q) a[o][q] = 0.f;
#pragma unroll 1
      for (int ic = 0; ic < 8; ++ic) {
        float win[4][6];
        const float* hrow = hs + (ic * 30 + r0) * HS_STRIDE + c0;
#pragma unroll
        for (int j = 0; j < 4; ++j)
#pragma unroll
          for (int k = 0; k < 6; ++k) win[j][k] = hrow[j * HS_STRIDE + k];
#pragma unroll
        for (int o = 0; o < 8; ++o) {
          const float* wt = w2 + ((oh * 8 + o) * 8 + ic) * 9;  // wave-uniform
          float w0_ = wt[0], w1_ = wt[1], w2_ = wt[2], w3_ = wt[3],
                w4_ = wt[4], w5_ = wt[5], w6_ = wt[6], w7_ = wt[7], w8_ = wt[8];
          a[o][0] += C9(0, 0); a[o][1] += C9(0, 1);
          a[o][2] += C9(1, 0); a[o][3] += C9(1, 1);
          a[o][4] += C9(0, 2); a[o][5] += C9(0, 3);
          a[o][6] += C9(1, 2); a[o][7] += C9(1, 3);
        }
      }
#pragma unroll
      for (int o = 0; o < 8; ++o) {
        int oc = oh * 8 + o;
        float bb = b2[oc];
        float m0 = fmaxf(fmaxf(a[o][0], a[o][1]), fmaxf(a[o][2], a[o][3]));
        float m1 = fmaxf(fmaxf(a[o][4], a[o][5]), fmaxf(a[o][6], a[o][7]));
        float f0 = fmaxf(m0 + bb, 0.f);  // f[oc][2ph+half][2pw]
        float f1 = fmaxf(m1 + bb, 0.f);  // f[oc][2ph+half][2pw+1]
#pragma unroll
        for (int ot = 0; ot < 4; ++ot) {
          partial[ot] += f0 * wp[ot * 64 + oc * 4 + half * 2] +
                         f1 * wp[ot * 64 + oc * 4 + half * 2 + 1];
        }
      }
    }
#pragma unroll
    for (int ot = 0; ot < 4; ++ot) pfh[p_l * 8 + half * 4 + ot] = partial[ot];
  }
  __syncthreads();

  // ---- Phase 3: combine halves + patch bias, write pf (coalesced) ----
  float* dst = pf + (long)b * 784 + s * 392;
  for (int t = tid; t < 392; t += 256) {
    int p = t >> 2, ot = t & 3;
    dst[t] = pfh[p * 8 + ot] + pfh[p * 8 + 4 + ot] + bp[ot];
  }
}

// ---------------- Kernel 2: fc1 + fc2 + log_softmax ------------------------
// One block per batch element, 256 threads. fc1: thread (j=tid/4, q=tid&3)
// reduces a 196-element quarter with float4, then width-4 shuffle combine.
__global__ __launch_bounds__(256) void k_fc(const float* __restrict__ pf,
                                            const float* __restrict__ w_fc1,
                                            const float* __restrict__ b_fc1,
                                            const float* __restrict__ w_fc2,
                                            const float* __restrict__ b_fc2,
                                            float* __restrict__ out) {
  __shared__ __align__(16) float pfs[784];
  __shared__ float h1s[64];
  __shared__ float lg[10];
  int tid = threadIdx.x;
  int b = blockIdx.x;

  if (tid < 196) ((float4*)pfs)[tid] = ((const float4*)(pf + (long)b * 784))[tid];
  __syncthreads();

  int j = tid >> 2, q = tid & 3;
  const float4* wj4 = (const float4*)(w_fc1 + j * 784 + q * 196);
  const float4* ps4 = (const float4*)(pfs + q * 196);
  float s = 0.f;
#pragma unroll 7
  for (int k = 0; k < 49; ++k) {
    float4 wv = wj4[k];
    float4 pv = ps4[k];
    s += wv.x * pv.x + wv.y * pv.y + wv.z * pv.z + wv.w * pv.w;
  }
  s += __shfl_down(s, 2, 4);
  s += __shfl_down(s, 1, 4);
  if (q == 0) h1s[j] = fmaxf(s + b_fc1[j], 0.f);
  __syncthreads();

  if (tid < 10) {
    float s2 = b_fc2[tid];
    const float* wo = w_fc2 + tid * 64;
#pragma unroll
    for (int k = 0; k < 64; ++k) s2 += h1s[k] * wo[k];
    lg[tid] = s2;
  }
  __syncthreads();

  if (tid == 0) {
    float mx = lg[0];
    for (int o = 1; o < 10; ++o) mx = fmaxf(mx, lg[o]);
    float se = 0.f;
    for (int o = 0; o < 10; ++o) se += expf(lg[o] - mx);
    float lse = mx + logf(se);
    for (int o = 0; o < 10; ++o) out[b * 10 + o] = lg[o] - lse;
  }
}

extern "C" void kernel_launch(void* const* d_in, const int* in_sizes, int n_in,
                              void* d_out, int out_size, void* d_ws, size_t ws_size,
                              hipStream_t stream) {
  const float* x = (const float*)d_in[0];
  const float* w1 = (const float*)d_in[1];
  const float* b1 = (const float*)d_in[2];
  const float* w2 = (const float*)d_in[3];
  const float* b2 = (const float*)d_in[4];
  const float* wp = (const float*)d_in[5];
  const float* bp = (const float*)d_in[6];
  const float* wf1 = (const float*)d_in[7];
  const float* bf1 = (const float*)d_in[8];
  const float* wf2 = (const float*)d_in[9];
  const float* bf2 = (const float*)d_in[10];

  float* pf = (float*)d_ws;  // pf[512,784] = 1.6 MB

  k_fused<<<dim3(1024), 256, 0, stream>>>(x, w1, b1, w2, b2, wp, bp, pf);
  k_fc<<<dim3(512), 256, 0, stream>>>(pf, wf1, bf1, wf2, bf2, (float*)d_out);
}